// Round 19
// baseline (115.890 us; speedup 1.0000x reference)
//
#include <hip/hip_runtime.h>
#include <math.h>

// Problem constants
#define KP   10      // prototypes per side
#define CC   768     // channels
#define NB   8       // batch
#define HW   4096    // 64*64
#define STOT 32768   // NB*HW
#define NS   12      // N_SAMPLES
#define NBLK 256     // k_scores blocks (128 px each)
#define NREG 8       // fe rows cached in registers per proto-wave

// Workspace layout (float offsets)
#define WS_CAND  0       // 2 sides x 256 blocks x 12 u64 = 6144 ull = 12288 floats
#define WS_FEATS 12352   // 24*768 floats (pos 12 rows, then neg 12 rows)
#define WS_PFG   30784   // 10*768
#define WS_PBG   38464   // 10*768

typedef unsigned long long ull;
typedef float f2v __attribute__((ext_vector_type(2)));

// packed 2-wide fma (v_pk_fma_f32); per-component order identical to scalar fmaf
__device__ __forceinline__ f2v fma2(f2v a, float b, f2v c) {
#if __has_builtin(__builtin_elementwise_fma)
    f2v bb = b;
    return __builtin_elementwise_fma(a, bb, c);
#else
    f2v r; r.x = fmaf(a.x, b, c.x); r.y = fmaf(a.y, b, c.y); return r;
#endif
}

// 64-lane sum on the VALU pipe (DPP); full sum lands in lane 63.
__device__ __forceinline__ float dpp_sum64(float x) {
#define DPP_ADD(ctrl) \
    x += __uint_as_float((unsigned)__builtin_amdgcn_update_dpp(0, (int)__float_as_uint(x), ctrl, 0xf, 0xf, true))
    DPP_ADD(0x111);  // row_shr:1
    DPP_ADD(0x112);  // row_shr:2
    DPP_ADD(0x114);  // row_shr:4
    DPP_ADD(0x118);  // row_shr:8
    DPP_ADD(0x142);  // row_bcast:15
    DPP_ADD(0x143);  // row_bcast:31
#undef DPP_ADD
    return x;        // lane 63 has the total
}
// broadcast lane 63's value to all lanes (uniform SGPR)
__device__ __forceinline__ float bcast63(float x) {
    return __uint_as_float((unsigned)__builtin_amdgcn_readlane((int)__float_as_uint(x), 63));
}

// Order-preserving float->uint map, packed with ~index: exact
// (value desc, index asc) under unsigned max; unique per pixel; 0 = empty.
__device__ __forceinline__ ull pack_key(float v, int idx) {
    unsigned u = __float_as_uint(v);
    u ^= (unsigned)((int)u >> 31) | 0x80000000u;
    return ((ull)u << 32) | (ull)(0xFFFFFFFFu - (unsigned)idx);
}

// ---------------- K1: scores + per-block top-12 candidates ----------------
// Depth-4 F prefetch (32 dwordx2 in flight per wave) to cover ~900cy miss
// latency at 4 waves/SIMD. Round loop fully unrolled -> static ring indices.
__global__ __launch_bounds__(1024) void k_scores(const float* __restrict__ fg,
                                                 const float* __restrict__ bg,
                                                 const float* __restrict__ F,
                                                 const float* __restrict__ M,
                                                 ull* __restrict__ cand) {
    __shared__ float pl[20 * CC];           // 61440 B
    __shared__ float part[8][64][2][21];    // 86016 B
    __shared__ ull kfl[128], kbl[128];      // 2048 B

    const int tid  = threadIdx.x;
    const int w    = __builtin_amdgcn_readfirstlane(tid >> 6);  // wave 0..15
    const int lane = tid & 63;
    const int b    = blockIdx.x;            // 0..255
    const int n    = b >> 5;                // 32 blocks per image
    const int hwb  = (b & 31) * 128 + lane * 2;
    const float* fp = F + ((size_t)n * CC) * HW + hwb;
    const int cbase = w * 48;

    // depth-4 prefetch ring (independent of LDS staging)
    f2v fn[4][8];
#pragma unroll
    for (int r = 0; r < 4; ++r)
#pragma unroll
        for (int j = 0; j < 8; ++j)
            fn[r][j] = __builtin_nontemporal_load((const f2v*)(fp + (size_t)(cbase + r * 8 + j) * HW));

    for (int i = tid; i < KP * CC; i += 1024) {
        pl[i]           = fg[i];
        pl[KP * CC + i] = bg[i];
    }
    __syncthreads();

    f2v afg[KP], abg[KP], n2;
#pragma unroll
    for (int k = 0; k < KP; ++k) { afg[k] = 0.f; abg[k] = 0.f; }
    n2 = 0.f;

#pragma unroll
    for (int c0 = 0; c0 < 6; ++c0) {        // 6 rounds x 8 channels, static ring idx
        f2v f[8];
#pragma unroll
        for (int j = 0; j < 8; ++j) f[j] = fn[c0 & 3][j];
        if (c0 + 4 < 6) {
#pragma unroll
            for (int j = 0; j < 8; ++j)
                fn[c0 & 3][j] = __builtin_nontemporal_load(
                    (const f2v*)(fp + (size_t)(cbase + (c0 + 4) * 8 + j) * HW));
        }

#pragma unroll
        for (int k = 0; k < KP; ++k) {
            const float4* pq = (const float4*)&pl[k * CC + cbase + c0 * 8];
            float4 a = pq[0], c = pq[1];
            f2v acc = afg[k];
            acc = fma2(f[0], a.x, acc); acc = fma2(f[1], a.y, acc);
            acc = fma2(f[2], a.z, acc); acc = fma2(f[3], a.w, acc);
            acc = fma2(f[4], c.x, acc); acc = fma2(f[5], c.y, acc);
            acc = fma2(f[6], c.z, acc); acc = fma2(f[7], c.w, acc);
            afg[k] = acc;
        }
#pragma unroll
        for (int k = 0; k < KP; ++k) {
            const float4* pq = (const float4*)&pl[(KP + k) * CC + cbase + c0 * 8];
            float4 a = pq[0], c = pq[1];
            f2v acc = abg[k];
            acc = fma2(f[0], a.x, acc); acc = fma2(f[1], a.y, acc);
            acc = fma2(f[2], a.z, acc); acc = fma2(f[3], a.w, acc);
            acc = fma2(f[4], c.x, acc); acc = fma2(f[5], c.y, acc);
            acc = fma2(f[6], c.z, acc); acc = fma2(f[7], c.w, acc);
            abg[k] = acc;
        }
#pragma unroll
        for (int j = 0; j < 8; ++j) {
#if __has_builtin(__builtin_elementwise_fma)
            n2 = __builtin_elementwise_fma(f[j], f[j], n2);
#else
            n2.x = fmaf(f[j].x, f[j].x, n2.x); n2.y = fmaf(f[j].y, f[j].y, n2.y);
#endif
        }
    }

    if (w >= 8) {
#pragma unroll
        for (int k = 0; k < KP; ++k) {
            part[w - 8][lane][0][k]      = afg[k].x; part[w - 8][lane][1][k]      = afg[k].y;
            part[w - 8][lane][0][10 + k] = abg[k].x; part[w - 8][lane][1][10 + k] = abg[k].y;
        }
        part[w - 8][lane][0][20] = n2.x; part[w - 8][lane][1][20] = n2.y;
    }
    __syncthreads();
    if (w < 8) {
#pragma unroll
        for (int k = 0; k < KP; ++k) {
            part[w][lane][0][k]      += afg[k].x; part[w][lane][1][k]      += afg[k].y;
            part[w][lane][0][10 + k] += abg[k].x; part[w][lane][1][10 + k] += abg[k].y;
        }
        part[w][lane][0][20] += n2.x; part[w][lane][1][20] += n2.y;
    }
    __syncthreads();

    if (tid < 128) {
        const int lane2 = tid >> 1, j = tid & 1;
        float vals[21];
#pragma unroll
        for (int q = 0; q < 21; ++q) {
            float acc = 0.f;
#pragma unroll
            for (int ss = 0; ss < 8; ++ss) acc += part[ss][lane2][j][q];
            vals[q] = acc;
        }
        float mfg = vals[0], mbg = vals[10];
#pragma unroll
        for (int k = 1; k < KP; ++k) { mfg = fmaxf(mfg, vals[k]); mbg = fmaxf(mbg, vals[10 + k]); }
        float nc = fmaxf(sqrtf(vals[20]), 1e-8f);
        int sp = b * 128 + tid;
        float m = fminf(fmaxf(M[sp], 0.f), 1.f);
        kfl[tid] = pack_key((1.f - mfg / nc) * m, sp);
        kbl[tid] = pack_key((1.f - mbg / nc) * (1.f - m), sp);
    }
    __syncthreads();

    if (w == 0) {
        ull k0 = kfl[lane], k1 = kfl[64 + lane];
        for (int r = 0; r < NS; ++r) {
            ull bk = (k0 > k1) ? k0 : k1;
#pragma unroll
            for (int m2 = 1; m2 < 64; m2 <<= 1) {
                ull o = __shfl_xor(bk, m2, 64);
                bk = (o > bk) ? o : bk;
            }
            if (lane == 0) cand[b * NS + r] = bk;
            if (k0 == bk) k0 = 0ull;
            if (k1 == bk) k1 = 0ull;
        }
    } else if (w == 1) {
        ull k0 = kbl[lane], k1 = kbl[64 + lane];
        for (int r = 0; r < NS; ++r) {
            ull bk = (k0 > k1) ? k0 : k1;
#pragma unroll
            for (int m2 = 1; m2 < 64; m2 <<= 1) {
                ull o = __shfl_xor(bk, m2, 64);
                bk = (o > bk) ? o : bk;
            }
            if (lane == 0) cand[NBLK * NS + b * NS + r] = bk;
            if (k0 == bk) k0 = 0ull;
            if (k1 == bk) k1 = 0ull;
        }
    }
}

// ---------------- K2: merge(redundant) + gather + normalize, 24 blocks ----
__global__ __launch_bounds__(256) void k_gather(const ull* __restrict__ cand,
                                                const float* __restrict__ F,
                                                float* __restrict__ feats) {
    __shared__ int   sel_sh;
    __shared__ float red[256];

    const int b    = blockIdx.x;            // 0..23
    const int side = b / NS, row = b - side * NS;
    const int tid  = threadIdx.x;
    const int wave = tid >> 6, lane = tid & 63;

    if (wave == 0) {
        const ull* cs = cand + side * (NBLK * NS);
        ull tv[NS];
#pragma unroll
        for (int q = 0; q < NS; ++q) tv[q] = 0ull;
        for (int c = 0; c < 48; ++c) {               // 3072 keys / 64 lanes
            ull key = cs[c * 64 + lane];
            if (key > tv[NS - 1]) {
#pragma unroll
                for (int q = NS - 1; q >= 1; --q) {
                    bool shift = key > tv[q - 1];
                    bool here  = !shift && (key > tv[q]);
                    tv[q] = shift ? tv[q - 1] : (here ? key : tv[q]);
                }
                if (key > tv[0]) tv[0] = key;
            }
        }
        ull win = 0ull;
        for (int r = 0; r <= row; ++r) {             // row uniform per block
            ull bk = tv[0];
#pragma unroll
            for (int m2 = 1; m2 < 64; m2 <<= 1) {
                ull o = __shfl_xor(bk, m2, 64);
                bk = (o > bk) ? o : bk;
            }
            if (r == row) win = bk;
            bool w0 = (tv[0] == bk);                 // keys unique -> one lane
#pragma unroll
            for (int q = 0; q < NS - 1; ++q) tv[q] = w0 ? tv[q + 1] : tv[q];
            tv[NS - 1] = w0 ? 0ull : tv[NS - 1];
        }
        if (lane == 0) sel_sh = (int)(0xFFFFFFFFu - (unsigned)(win & 0xFFFFFFFFull));
    }
    __syncthreads();

    const int sp = sel_sh;
    const float* fp = F + ((size_t)(sp >> 12) * CC) * HW + (sp & 4095);
    float v0 = fp[(size_t)(tid)       * HW];
    float v1 = fp[(size_t)(tid + 256) * HW];
    float v2 = fp[(size_t)(tid + 512) * HW];
    red[tid] = v0 * v0 + v1 * v1 + v2 * v2;
    __syncthreads();
    for (int off = 128; off > 0; off >>= 1) { if (tid < off) red[tid] += red[tid + off]; __syncthreads(); }
    float inv = 1.f / fmaxf(sqrtf(red[0]), 1e-8f);
    float* fo = feats + (side * NS + row) * CC;
    fo[tid]       = v0 * inv;
    fo[tid + 256] = v1 * inv;
    fo[tid + 512] = v2 * inv;
}

// ---- K3: refine + blend (2 blocks x 640 = 10 proto-waves) ----
__global__ __launch_bounds__(640) void k_refine(const float* __restrict__ feats,
                                                const float* __restrict__ fg,
                                                const float* __restrict__ bg,
                                                float* __restrict__ pfg,
                                                float* __restrict__ pbg,
                                                float* __restrict__ out) {
    __shared__ float fe[NS * CC];   // 36 KB
    __shared__ float dots[NS][KP];
    __shared__ int   assign[NS];

    const int side = blockIdx.x;
    const int tid  = threadIdx.x;
    const int wave = __builtin_amdgcn_readfirstlane(tid >> 6);  // 0..9 (= proto id)
    const int lane = tid & 63;
    const int k    = wave;
    const float* p0 = (side == 0) ? fg : bg;
    float* pout     = (side == 0) ? pfg : pbg;

    {
        const float4* fi = (const float4*)(feats + side * (NS * CC));
        float4* fl = (float4*)fe;
        for (int i = tid; i < NS * CC / 4; i += 640) fl[i] = fi[i];
    }
    __syncthreads();

    float4 fer[NREG][3];
#pragma unroll
    for (int s = 0; s < NREG; ++s)
#pragma unroll
        for (int j4 = 0; j4 < 3; ++j4)
            fer[s][j4] = *(const float4*)&fe[s * CC + j4 * 256 + lane * 4];

    float4 p[3];
#pragma unroll
    for (int j4 = 0; j4 < 3; ++j4)
        p[j4] = *(const float4*)&p0[k * CC + j4 * 256 + lane * 4];

    for (int it = 0; it < 10; ++it) {
        float step = 0.1f / (1.0f + 0.5f * (float)it);

        float d[NS];
#pragma unroll
        for (int s = 0; s < NS; ++s) d[s] = 0.f;
#pragma unroll
        for (int j4 = 0; j4 < 3; ++j4) {
            float4 pv = p[j4];
#pragma unroll
            for (int s = 0; s < NREG; ++s) {
                float4 fv = fer[s][j4];
                d[s] = fmaf(fv.x, pv.x, d[s]);
                d[s] = fmaf(fv.y, pv.y, d[s]);
                d[s] = fmaf(fv.z, pv.z, d[s]);
                d[s] = fmaf(fv.w, pv.w, d[s]);
            }
#pragma unroll
            for (int s = NREG; s < NS; ++s) {
                float4 fv = *(const float4*)&fe[s * CC + j4 * 256 + lane * 4];
                d[s] = fmaf(fv.x, pv.x, d[s]);
                d[s] = fmaf(fv.y, pv.y, d[s]);
                d[s] = fmaf(fv.z, pv.z, d[s]);
                d[s] = fmaf(fv.w, pv.w, d[s]);
            }
        }
#pragma unroll
        for (int s = 0; s < NS; ++s) d[s] = dpp_sum64(d[s]);   // VALU-pipe reduce
        if (lane == 63) {
#pragma unroll
            for (int s = 0; s < NS; ++s) dots[s][k] = d[s];
        }
        __syncthreads();

        if (tid < NS) {
            float bv = dots[tid][0]; int bk = 0;
#pragma unroll
            for (int kk = 1; kk < KP; ++kk) { float v = dots[tid][kk]; if (v > bv) { bv = v; bk = kk; } }
            assign[tid] = bk;
        }
        __syncthreads();

        int a[NS]; int cnt = 0;
#pragma unroll
        for (int s = 0; s < NS; ++s) { a[s] = assign[s]; cnt += (a[s] == k) ? 1 : 0; }

        if (cnt > 0) {
            float4 mac[3];
#pragma unroll
            for (int j4 = 0; j4 < 3; ++j4) mac[j4] = make_float4(0.f, 0.f, 0.f, 0.f);
#pragma unroll
            for (int s = 0; s < NREG; ++s) {
                if (a[s] == k) {   // wave-uniform branch
#pragma unroll
                    for (int j4 = 0; j4 < 3; ++j4) {
                        float4 fv = fer[s][j4];
                        mac[j4].x += fv.x; mac[j4].y += fv.y; mac[j4].z += fv.z; mac[j4].w += fv.w;
                    }
                }
            }
#pragma unroll
            for (int s = NREG; s < NS; ++s) {
                if (a[s] == k) {
#pragma unroll
                    for (int j4 = 0; j4 < 3; ++j4) {
                        float4 fv = *(const float4*)&fe[s * CC + j4 * 256 + lane * 4];
                        mac[j4].x += fv.x; mac[j4].y += fv.y; mac[j4].z += fv.z; mac[j4].w += fv.w;
                    }
                }
            }
            float fcnt = (float)cnt;
            float4 v[3]; float ss = 0.f;
#pragma unroll
            for (int j4 = 0; j4 < 3; ++j4) {
                v[j4].x = (1.0f - step) * p[j4].x + step * (mac[j4].x / fcnt);
                v[j4].y = (1.0f - step) * p[j4].y + step * (mac[j4].y / fcnt);
                v[j4].z = (1.0f - step) * p[j4].z + step * (mac[j4].z / fcnt);
                v[j4].w = (1.0f - step) * p[j4].w + step * (mac[j4].w / fcnt);
                ss = fmaf(v[j4].x, v[j4].x, ss);
                ss = fmaf(v[j4].y, v[j4].y, ss);
                ss = fmaf(v[j4].z, v[j4].z, ss);
                ss = fmaf(v[j4].w, v[j4].w, ss);
            }
            float tot = bcast63(dpp_sum64(ss));
            float inv = 1.f / fmaxf(sqrtf(tot), 1e-8f);
#pragma unroll
            for (int j4 = 0; j4 < 3; ++j4) {
                p[j4].x = v[j4].x * inv; p[j4].y = v[j4].y * inv;
                p[j4].z = v[j4].z * inv; p[j4].w = v[j4].w * inv;
            }
        }
    }

#pragma unroll
    for (int j4 = 0; j4 < 3; ++j4)
        *(float4*)&pout[k * CC + j4 * 256 + lane * 4] = p[j4];

    float4 vv[3]; float ss2 = 0.f;
#pragma unroll
    for (int j4 = 0; j4 < 3; ++j4) {
        float4 pz = *(const float4*)&p0[k * CC + j4 * 256 + lane * 4];
        vv[j4].x = 0.7f * pz.x + 0.3f * p[j4].x;
        vv[j4].y = 0.7f * pz.y + 0.3f * p[j4].y;
        vv[j4].z = 0.7f * pz.z + 0.3f * p[j4].z;
        vv[j4].w = 0.7f * pz.w + 0.3f * p[j4].w;
        ss2 = fmaf(vv[j4].x, vv[j4].x, ss2);
        ss2 = fmaf(vv[j4].y, vv[j4].y, ss2);
        ss2 = fmaf(vv[j4].z, vv[j4].z, ss2);
        ss2 = fmaf(vv[j4].w, vv[j4].w, ss2);
    }
    float tot2 = bcast63(dpp_sum64(ss2));
    float inv2 = 1.f / fmaxf(sqrtf(tot2), 1e-8f);
    float* orow = out + 1 + (side * KP + k) * CC;
#pragma unroll
    for (int j4 = 0; j4 < 3; ++j4) {
        float4 o4;
        o4.x = vv[j4].x * inv2; o4.y = vv[j4].y * inv2;
        o4.z = vv[j4].z * inv2; o4.w = vv[j4].w * inv2;
        *(float4*)&orow[j4 * 256 + lane * 4] = o4;
    }
}

// ---------------- K4: loss (1 block, 16 waves; DPP reductions) ----------------
__global__ __launch_bounds__(1024) void k_loss(const float* __restrict__ feats,
                                               const float* __restrict__ pfg,
                                               const float* __restrict__ pbg,
                                               float* __restrict__ out) {
    __shared__ float dots3[NS * 30];   // [s][g*10+k]: g=0 pos@pfg, g=1 neg@pfg, g=2 pos@pbg
    __shared__ float mp[NS], mn[NS], infon[NS];
    int tid = threadIdx.x, wave = tid >> 6, lane = tid & 63;

    for (int pid = wave; pid < 360; pid += 16) {
        int g = pid / 120, rr = pid % 120, s = rr / KP, k = rr % KP;
        const float4* a4 = (const float4*)(feats + ((g == 1 ? NS + s : s) * CC) + lane * 12);
        const float4* b4 = (const float4*)((g == 2 ? pbg : pfg) + k * CC + lane * 12);
        float acc = 0.f;
#pragma unroll
        for (int j = 0; j < 3; ++j) {
            float4 a = a4[j], b = b4[j];
            acc += a.x * b.x + a.y * b.y + a.z * b.z + a.w * b.w;
        }
        acc = dpp_sum64(acc);
        if (lane == 63) dots3[s * 30 + g * 10 + k] = acc;
    }
    __syncthreads();

    if (tid < NS) {
        const float* d = &dots3[tid * 30];
        float maxp = d[0], maxn = d[10];
#pragma unroll
        for (int k = 1; k < KP; ++k) { maxp = fmaxf(maxp, d[k]); maxn = fmaxf(maxn, d[10 + k]); }
        mp[tid] = maxp; mn[tid] = maxn;

        float x[KP], y[KP];
#pragma unroll
        for (int k = 0; k < KP; ++k) { x[k] = d[k] / 0.07f; y[k] = d[20 + k] / 0.07f; }
        float m10 = x[0];
#pragma unroll
        for (int k = 1; k < KP; ++k) m10 = fmaxf(m10, x[k]);
        float se = 0.f;
#pragma unroll
        for (int k = 0; k < KP; ++k) se += expf(x[k] - m10);
        float numer = logf(se) + m10;
        float m20 = m10;
#pragma unroll
        for (int k = 0; k < KP; ++k) m20 = fmaxf(m20, y[k]);
        float se2 = 0.f;
#pragma unroll
        for (int k = 0; k < KP; ++k) se2 += expf(x[k] - m20);
#pragma unroll
        for (int k = 0; k < KP; ++k) se2 += expf(y[k] - m20);
        float denom = logf(se2) + m20;
        infon[tid] = numer - denom;
    }
    __syncthreads();
    if (tid == 0) {
        float sp = 0.f, sn = 0.f, si = 0.f;
        for (int s = 0; s < NS; ++s) { sp += mp[s]; sn += mn[s]; si += infon[s]; }
        sp /= 12.f; sn /= 12.f; si /= 12.f;
        float loss = fmaxf(0.2f + sn - sp, 0.f) + 0.25f * (-si);
        out[0] = loss;
    }
}

extern "C" void kernel_launch(void* const* d_in, const int* in_sizes, int n_in,
                              void* d_out, int out_size, void* d_ws, size_t ws_size,
                              hipStream_t stream) {
    const float* fg = (const float*)d_in[0];   // [10,768]
    const float* bg = (const float*)d_in[1];   // [10,768]
    const float* F  = (const float*)d_in[2];   // [8,768,64,64]
    const float* M  = (const float*)d_in[3];   // [8,1,64,64]
    float* out = (float*)d_out;                // [1 + 7680 + 7680]

    float* w    = (float*)d_ws;
    ull*   cand = (ull*)(w + WS_CAND);
    float* fea  = w + WS_FEATS;
    float* pfg  = w + WS_PFG;
    float* pbg  = w + WS_PBG;

    k_scores<<<NBLK, 1024, 0, stream>>>(fg, bg, F, M, cand);
    k_gather<<<24, 256, 0, stream>>>(cand, F, fea);
    k_refine<<<2, 640, 0, stream>>>(fea, fg, bg, pfg, pbg, out);
    k_loss  <<<1, 1024, 0, stream>>>(fea, pfg, pbg, out);
}

// Round 20
// 110.989 us; speedup vs baseline: 1.0442x; 1.0442x over previous
//
#include <hip/hip_runtime.h>
#include <math.h>

// Problem constants
#define KP   10      // prototypes per side
#define CC   768     // channels
#define NB   8       // batch
#define HW   4096    // 64*64
#define STOT 32768   // NB*HW
#define NS   12      // N_SAMPLES
#define NBLK 256     // k_scores blocks (128 px each)
#define NREG 8       // fe rows cached in registers per proto-wave

// Workspace layout (float offsets)
#define WS_CAND  0       // 2 sides x 256 blocks x 12 u64 = 6144 ull = 12288 floats
#define WS_FEATS 12352   // 24*768 floats (pos 12 rows, then neg 12 rows)
#define WS_PFG   30784   // 10*768
#define WS_PBG   38464   // 10*768

typedef unsigned long long ull;
typedef float f2v __attribute__((ext_vector_type(2)));

// packed 2-wide fma (v_pk_fma_f32); per-component order identical to scalar fmaf
__device__ __forceinline__ f2v fma2(f2v a, float b, f2v c) {
#if __has_builtin(__builtin_elementwise_fma)
    f2v bb = b;
    return __builtin_elementwise_fma(a, bb, c);
#else
    f2v r; r.x = fmaf(a.x, b, c.x); r.y = fmaf(a.y, b, c.y); return r;
#endif
}

// 64-lane sum on the VALU pipe (DPP); full sum lands in lane 63.
__device__ __forceinline__ float dpp_sum64(float x) {
#define DPP_ADD(ctrl) \
    x += __uint_as_float((unsigned)__builtin_amdgcn_update_dpp(0, (int)__float_as_uint(x), ctrl, 0xf, 0xf, true))
    DPP_ADD(0x111);  // row_shr:1
    DPP_ADD(0x112);  // row_shr:2
    DPP_ADD(0x114);  // row_shr:4
    DPP_ADD(0x118);  // row_shr:8
    DPP_ADD(0x142);  // row_bcast:15
    DPP_ADD(0x143);  // row_bcast:31
#undef DPP_ADD
    return x;        // lane 63 has the total
}
// broadcast lane 63's value to all lanes (uniform SGPR)
__device__ __forceinline__ float bcast63(float x) {
    return __uint_as_float((unsigned)__builtin_amdgcn_readlane((int)__float_as_uint(x), 63));
}

// Order-preserving float->uint map, packed with ~index: exact
// (value desc, index asc) under unsigned max; unique per pixel; 0 = empty.
__device__ __forceinline__ ull pack_key(float v, int idx) {
    unsigned u = __float_as_uint(v);
    u ^= (unsigned)((int)u >> 31) | 0x80000000u;
    return ((ull)u << 32) | (ull)(0xFFFFFFFFu - (unsigned)idx);
}

// ---------------- K1: scores + per-block top-12 candidates ----------------
// R18 configuration (best measured): depth-2 F prefetch, LDS protos,
// packed-f32 accumulators, barrier-free per-block selection.
// Micro: proto staging vectorized to float4.
__global__ __launch_bounds__(1024) void k_scores(const float* __restrict__ fg,
                                                 const float* __restrict__ bg,
                                                 const float* __restrict__ F,
                                                 const float* __restrict__ M,
                                                 ull* __restrict__ cand) {
    __shared__ float pl[20 * CC];           // 61440 B
    __shared__ float part[8][64][2][21];    // 86016 B
    __shared__ ull kfl[128], kbl[128];      // 2048 B

    const int tid  = threadIdx.x;
    const int w    = __builtin_amdgcn_readfirstlane(tid >> 6);  // wave 0..15
    const int lane = tid & 63;
    const int b    = blockIdx.x;            // 0..255
    const int n    = b >> 5;                // 32 blocks per image
    const int hwb  = (b & 31) * 128 + lane * 2;
    const float* fp = F + ((size_t)n * CC) * HW + hwb;
    const int cbase = w * 48;

    f2v fnA[8], fnB[8];
#pragma unroll
    for (int j = 0; j < 8; ++j)
        fnA[j] = __builtin_nontemporal_load((const f2v*)(fp + (size_t)(cbase + j) * HW));
#pragma unroll
    for (int j = 0; j < 8; ++j)
        fnB[j] = __builtin_nontemporal_load((const f2v*)(fp + (size_t)(cbase + 8 + j) * HW));

    // stage protos to LDS (float4 vectorized: 3840 float4 over 1024 threads)
    {
        const float4* fg4 = (const float4*)fg;
        const float4* bg4 = (const float4*)bg;
        float4* pl4a = (float4*)pl;
        float4* pl4b = (float4*)(pl + KP * CC);
        for (int i = tid; i < KP * CC / 4; i += 1024) {
            pl4a[i] = fg4[i];
            pl4b[i] = bg4[i];
        }
    }
    __syncthreads();

    f2v afg[KP], abg[KP], n2;
#pragma unroll
    for (int k = 0; k < KP; ++k) { afg[k] = 0.f; abg[k] = 0.f; }
    n2 = 0.f;

    for (int c0 = 0; c0 < 48; c0 += 8) {
        f2v f[8];
#pragma unroll
        for (int j = 0; j < 8; ++j) { f[j] = fnA[j]; fnA[j] = fnB[j]; }
        if (c0 + 16 < 48) {
#pragma unroll
            for (int j = 0; j < 8; ++j)
                fnB[j] = __builtin_nontemporal_load((const f2v*)(fp + (size_t)(cbase + c0 + 16 + j) * HW));
        }

#pragma unroll
        for (int k = 0; k < KP; ++k) {
            const float4* pq = (const float4*)&pl[k * CC + cbase + c0];
            float4 a = pq[0], c = pq[1];
            f2v acc = afg[k];
            acc = fma2(f[0], a.x, acc); acc = fma2(f[1], a.y, acc);
            acc = fma2(f[2], a.z, acc); acc = fma2(f[3], a.w, acc);
            acc = fma2(f[4], c.x, acc); acc = fma2(f[5], c.y, acc);
            acc = fma2(f[6], c.z, acc); acc = fma2(f[7], c.w, acc);
            afg[k] = acc;
        }
#pragma unroll
        for (int k = 0; k < KP; ++k) {
            const float4* pq = (const float4*)&pl[(KP + k) * CC + cbase + c0];
            float4 a = pq[0], c = pq[1];
            f2v acc = abg[k];
            acc = fma2(f[0], a.x, acc); acc = fma2(f[1], a.y, acc);
            acc = fma2(f[2], a.z, acc); acc = fma2(f[3], a.w, acc);
            acc = fma2(f[4], c.x, acc); acc = fma2(f[5], c.y, acc);
            acc = fma2(f[6], c.z, acc); acc = fma2(f[7], c.w, acc);
            abg[k] = acc;
        }
#pragma unroll
        for (int j = 0; j < 8; ++j) {
#if __has_builtin(__builtin_elementwise_fma)
            n2 = __builtin_elementwise_fma(f[j], f[j], n2);
#else
            n2.x = fmaf(f[j].x, f[j].x, n2.x); n2.y = fmaf(f[j].y, f[j].y, n2.y);
#endif
        }
    }

    if (w >= 8) {
#pragma unroll
        for (int k = 0; k < KP; ++k) {
            part[w - 8][lane][0][k]      = afg[k].x; part[w - 8][lane][1][k]      = afg[k].y;
            part[w - 8][lane][0][10 + k] = abg[k].x; part[w - 8][lane][1][10 + k] = abg[k].y;
        }
        part[w - 8][lane][0][20] = n2.x; part[w - 8][lane][1][20] = n2.y;
    }
    __syncthreads();
    if (w < 8) {
#pragma unroll
        for (int k = 0; k < KP; ++k) {
            part[w][lane][0][k]      += afg[k].x; part[w][lane][1][k]      += afg[k].y;
            part[w][lane][0][10 + k] += abg[k].x; part[w][lane][1][10 + k] += abg[k].y;
        }
        part[w][lane][0][20] += n2.x; part[w][lane][1][20] += n2.y;
    }
    __syncthreads();

    if (tid < 128) {
        const int lane2 = tid >> 1, j = tid & 1;
        float vals[21];
#pragma unroll
        for (int q = 0; q < 21; ++q) {
            float acc = 0.f;
#pragma unroll
            for (int ss = 0; ss < 8; ++ss) acc += part[ss][lane2][j][q];
            vals[q] = acc;
        }
        float mfg = vals[0], mbg = vals[10];
#pragma unroll
        for (int k = 1; k < KP; ++k) { mfg = fmaxf(mfg, vals[k]); mbg = fmaxf(mbg, vals[10 + k]); }
        float nc = fmaxf(sqrtf(vals[20]), 1e-8f);
        int sp = b * 128 + tid;
        float m = fminf(fmaxf(M[sp], 0.f), 1.f);
        kfl[tid] = pack_key((1.f - mfg / nc) * m, sp);
        kbl[tid] = pack_key((1.f - mbg / nc) * (1.f - m), sp);
    }
    __syncthreads();

    if (w == 0) {
        ull k0 = kfl[lane], k1 = kfl[64 + lane];
        for (int r = 0; r < NS; ++r) {
            ull bk = (k0 > k1) ? k0 : k1;
#pragma unroll
            for (int m2 = 1; m2 < 64; m2 <<= 1) {
                ull o = __shfl_xor(bk, m2, 64);
                bk = (o > bk) ? o : bk;
            }
            if (lane == 0) cand[b * NS + r] = bk;
            if (k0 == bk) k0 = 0ull;
            if (k1 == bk) k1 = 0ull;
        }
    } else if (w == 1) {
        ull k0 = kbl[lane], k1 = kbl[64 + lane];
        for (int r = 0; r < NS; ++r) {
            ull bk = (k0 > k1) ? k0 : k1;
#pragma unroll
            for (int m2 = 1; m2 < 64; m2 <<= 1) {
                ull o = __shfl_xor(bk, m2, 64);
                bk = (o > bk) ? o : bk;
            }
            if (lane == 0) cand[NBLK * NS + b * NS + r] = bk;
            if (k0 == bk) k0 = 0ull;
            if (k1 == bk) k1 = 0ull;
        }
    }
}

// ---------------- K2: merge(redundant) + gather + normalize, 24 blocks ----
__global__ __launch_bounds__(256) void k_gather(const ull* __restrict__ cand,
                                                const float* __restrict__ F,
                                                float* __restrict__ feats) {
    __shared__ int   sel_sh;
    __shared__ float red[256];

    const int b    = blockIdx.x;            // 0..23
    const int side = b / NS, row = b - side * NS;
    const int tid  = threadIdx.x;
    const int wave = tid >> 6, lane = tid & 63;

    if (wave == 0) {
        const ull* cs = cand + side * (NBLK * NS);
        ull tv[NS];
#pragma unroll
        for (int q = 0; q < NS; ++q) tv[q] = 0ull;
        for (int c = 0; c < 48; ++c) {               // 3072 keys / 64 lanes
            ull key = cs[c * 64 + lane];
            if (key > tv[NS - 1]) {
#pragma unroll
                for (int q = NS - 1; q >= 1; --q) {
                    bool shift = key > tv[q - 1];
                    bool here  = !shift && (key > tv[q]);
                    tv[q] = shift ? tv[q - 1] : (here ? key : tv[q]);
                }
                if (key > tv[0]) tv[0] = key;
            }
        }
        ull win = 0ull;
        for (int r = 0; r <= row; ++r) {             // row uniform per block
            ull bk = tv[0];
#pragma unroll
            for (int m2 = 1; m2 < 64; m2 <<= 1) {
                ull o = __shfl_xor(bk, m2, 64);
                bk = (o > bk) ? o : bk;
            }
            if (r == row) win = bk;
            bool w0 = (tv[0] == bk);                 // keys unique -> one lane
#pragma unroll
            for (int q = 0; q < NS - 1; ++q) tv[q] = w0 ? tv[q + 1] : tv[q];
            tv[NS - 1] = w0 ? 0ull : tv[NS - 1];
        }
        if (lane == 0) sel_sh = (int)(0xFFFFFFFFu - (unsigned)(win & 0xFFFFFFFFull));
    }
    __syncthreads();

    const int sp = sel_sh;
    const float* fp = F + ((size_t)(sp >> 12) * CC) * HW + (sp & 4095);
    float v0 = fp[(size_t)(tid)       * HW];
    float v1 = fp[(size_t)(tid + 256) * HW];
    float v2 = fp[(size_t)(tid + 512) * HW];
    red[tid] = v0 * v0 + v1 * v1 + v2 * v2;
    __syncthreads();
    for (int off = 128; off > 0; off >>= 1) { if (tid < off) red[tid] += red[tid + off]; __syncthreads(); }
    float inv = 1.f / fmaxf(sqrtf(red[0]), 1e-8f);
    float* fo = feats + (side * NS + row) * CC;
    fo[tid]       = v0 * inv;
    fo[tid + 256] = v1 * inv;
    fo[tid + 512] = v2 * inv;
}

// ---- K3: refine + blend (2 blocks x 640 = 10 proto-waves) ----
__global__ __launch_bounds__(640) void k_refine(const float* __restrict__ feats,
                                                const float* __restrict__ fg,
                                                const float* __restrict__ bg,
                                                float* __restrict__ pfg,
                                                float* __restrict__ pbg,
                                                float* __restrict__ out) {
    __shared__ float fe[NS * CC];   // 36 KB
    __shared__ float dots[NS][KP];
    __shared__ int   assign[NS];

    const int side = blockIdx.x;
    const int tid  = threadIdx.x;
    const int wave = __builtin_amdgcn_readfirstlane(tid >> 6);  // 0..9 (= proto id)
    const int lane = tid & 63;
    const int k    = wave;
    const float* p0 = (side == 0) ? fg : bg;
    float* pout     = (side == 0) ? pfg : pbg;

    {
        const float4* fi = (const float4*)(feats + side * (NS * CC));
        float4* fl = (float4*)fe;
        for (int i = tid; i < NS * CC / 4; i += 640) fl[i] = fi[i];
    }
    __syncthreads();

    float4 fer[NREG][3];
#pragma unroll
    for (int s = 0; s < NREG; ++s)
#pragma unroll
        for (int j4 = 0; j4 < 3; ++j4)
            fer[s][j4] = *(const float4*)&fe[s * CC + j4 * 256 + lane * 4];

    float4 p[3];
#pragma unroll
    for (int j4 = 0; j4 < 3; ++j4)
        p[j4] = *(const float4*)&p0[k * CC + j4 * 256 + lane * 4];

    for (int it = 0; it < 10; ++it) {
        float step = 0.1f / (1.0f + 0.5f * (float)it);

        float d[NS];
#pragma unroll
        for (int s = 0; s < NS; ++s) d[s] = 0.f;
#pragma unroll
        for (int j4 = 0; j4 < 3; ++j4) {
            float4 pv = p[j4];
#pragma unroll
            for (int s = 0; s < NREG; ++s) {
                float4 fv = fer[s][j4];
                d[s] = fmaf(fv.x, pv.x, d[s]);
                d[s] = fmaf(fv.y, pv.y, d[s]);
                d[s] = fmaf(fv.z, pv.z, d[s]);
                d[s] = fmaf(fv.w, pv.w, d[s]);
            }
#pragma unroll
            for (int s = NREG; s < NS; ++s) {
                float4 fv = *(const float4*)&fe[s * CC + j4 * 256 + lane * 4];
                d[s] = fmaf(fv.x, pv.x, d[s]);
                d[s] = fmaf(fv.y, pv.y, d[s]);
                d[s] = fmaf(fv.z, pv.z, d[s]);
                d[s] = fmaf(fv.w, pv.w, d[s]);
            }
        }
#pragma unroll
        for (int s = 0; s < NS; ++s) d[s] = dpp_sum64(d[s]);   // VALU-pipe reduce
        if (lane == 63) {
#pragma unroll
            for (int s = 0; s < NS; ++s) dots[s][k] = d[s];
        }
        __syncthreads();

        if (tid < NS) {
            float bv = dots[tid][0]; int bk = 0;
#pragma unroll
            for (int kk = 1; kk < KP; ++kk) { float v = dots[tid][kk]; if (v > bv) { bv = v; bk = kk; } }
            assign[tid] = bk;
        }
        __syncthreads();

        int a[NS]; int cnt = 0;
#pragma unroll
        for (int s = 0; s < NS; ++s) { a[s] = assign[s]; cnt += (a[s] == k) ? 1 : 0; }

        if (cnt > 0) {
            float4 mac[3];
#pragma unroll
            for (int j4 = 0; j4 < 3; ++j4) mac[j4] = make_float4(0.f, 0.f, 0.f, 0.f);
#pragma unroll
            for (int s = 0; s < NREG; ++s) {
                if (a[s] == k) {   // wave-uniform branch
#pragma unroll
                    for (int j4 = 0; j4 < 3; ++j4) {
                        float4 fv = fer[s][j4];
                        mac[j4].x += fv.x; mac[j4].y += fv.y; mac[j4].z += fv.z; mac[j4].w += fv.w;
                    }
                }
            }
#pragma unroll
            for (int s = NREG; s < NS; ++s) {
                if (a[s] == k) {
#pragma unroll
                    for (int j4 = 0; j4 < 3; ++j4) {
                        float4 fv = *(const float4*)&fe[s * CC + j4 * 256 + lane * 4];
                        mac[j4].x += fv.x; mac[j4].y += fv.y; mac[j4].z += fv.z; mac[j4].w += fv.w;
                    }
                }
            }
            float fcnt = (float)cnt;
            float4 v[3]; float ss = 0.f;
#pragma unroll
            for (int j4 = 0; j4 < 3; ++j4) {
                v[j4].x = (1.0f - step) * p[j4].x + step * (mac[j4].x / fcnt);
                v[j4].y = (1.0f - step) * p[j4].y + step * (mac[j4].y / fcnt);
                v[j4].z = (1.0f - step) * p[j4].z + step * (mac[j4].z / fcnt);
                v[j4].w = (1.0f - step) * p[j4].w + step * (mac[j4].w / fcnt);
                ss = fmaf(v[j4].x, v[j4].x, ss);
                ss = fmaf(v[j4].y, v[j4].y, ss);
                ss = fmaf(v[j4].z, v[j4].z, ss);
                ss = fmaf(v[j4].w, v[j4].w, ss);
            }
            float tot = bcast63(dpp_sum64(ss));
            float inv = 1.f / fmaxf(sqrtf(tot), 1e-8f);
#pragma unroll
            for (int j4 = 0; j4 < 3; ++j4) {
                p[j4].x = v[j4].x * inv; p[j4].y = v[j4].y * inv;
                p[j4].z = v[j4].z * inv; p[j4].w = v[j4].w * inv;
            }
        }
    }

#pragma unroll
    for (int j4 = 0; j4 < 3; ++j4)
        *(float4*)&pout[k * CC + j4 * 256 + lane * 4] = p[j4];

    float4 vv[3]; float ss2 = 0.f;
#pragma unroll
    for (int j4 = 0; j4 < 3; ++j4) {
        float4 pz = *(const float4*)&p0[k * CC + j4 * 256 + lane * 4];
        vv[j4].x = 0.7f * pz.x + 0.3f * p[j4].x;
        vv[j4].y = 0.7f * pz.y + 0.3f * p[j4].y;
        vv[j4].z = 0.7f * pz.z + 0.3f * p[j4].z;
        vv[j4].w = 0.7f * pz.w + 0.3f * p[j4].w;
        ss2 = fmaf(vv[j4].x, vv[j4].x, ss2);
        ss2 = fmaf(vv[j4].y, vv[j4].y, ss2);
        ss2 = fmaf(vv[j4].z, vv[j4].z, ss2);
        ss2 = fmaf(vv[j4].w, vv[j4].w, ss2);
    }
    float tot2 = bcast63(dpp_sum64(ss2));
    float inv2 = 1.f / fmaxf(sqrtf(tot2), 1e-8f);
    float* orow = out + 1 + (side * KP + k) * CC;
#pragma unroll
    for (int j4 = 0; j4 < 3; ++j4) {
        float4 o4;
        o4.x = vv[j4].x * inv2; o4.y = vv[j4].y * inv2;
        o4.z = vv[j4].z * inv2; o4.w = vv[j4].w * inv2;
        *(float4*)&orow[j4 * 256 + lane * 4] = o4;
    }
}

// ---------------- K4: loss (1 block, 16 waves; DPP reductions) ----------------
__global__ __launch_bounds__(1024) void k_loss(const float* __restrict__ feats,
                                               const float* __restrict__ pfg,
                                               const float* __restrict__ pbg,
                                               float* __restrict__ out) {
    __shared__ float dots3[NS * 30];   // [s][g*10+k]: g=0 pos@pfg, g=1 neg@pfg, g=2 pos@pbg
    __shared__ float mp[NS], mn[NS], infon[NS];
    int tid = threadIdx.x, wave = tid >> 6, lane = tid & 63;

    for (int pid = wave; pid < 360; pid += 16) {
        int g = pid / 120, rr = pid % 120, s = rr / KP, k = rr % KP;
        const float4* a4 = (const float4*)(feats + ((g == 1 ? NS + s : s) * CC) + lane * 12);
        const float4* b4 = (const float4*)((g == 2 ? pbg : pfg) + k * CC + lane * 12);
        float acc = 0.f;
#pragma unroll
        for (int j = 0; j < 3; ++j) {
            float4 a = a4[j], b = b4[j];
            acc += a.x * b.x + a.y * b.y + a.z * b.z + a.w * b.w;
        }
        acc = dpp_sum64(acc);
        if (lane == 63) dots3[s * 30 + g * 10 + k] = acc;
    }
    __syncthreads();

    if (tid < NS) {
        const float* d = &dots3[tid * 30];
        float maxp = d[0], maxn = d[10];
#pragma unroll
        for (int k = 1; k < KP; ++k) { maxp = fmaxf(maxp, d[k]); maxn = fmaxf(maxn, d[10 + k]); }
        mp[tid] = maxp; mn[tid] = maxn;

        float x[KP], y[KP];
#pragma unroll
        for (int k = 0; k < KP; ++k) { x[k] = d[k] / 0.07f; y[k] = d[20 + k] / 0.07f; }
        float m10 = x[0];
#pragma unroll
        for (int k = 1; k < KP; ++k) m10 = fmaxf(m10, x[k]);
        float se = 0.f;
#pragma unroll
        for (int k = 0; k < KP; ++k) se += expf(x[k] - m10);
        float numer = logf(se) + m10;
        float m20 = m10;
#pragma unroll
        for (int k = 0; k < KP; ++k) m20 = fmaxf(m20, y[k]);
        float se2 = 0.f;
#pragma unroll
        for (int k = 0; k < KP; ++k) se2 += expf(x[k] - m20);
#pragma unroll
        for (int k = 0; k < KP; ++k) se2 += expf(y[k] - m20);
        float denom = logf(se2) + m20;
        infon[tid] = numer - denom;
    }
    __syncthreads();
    if (tid == 0) {
        float sp = 0.f, sn = 0.f, si = 0.f;
        for (int s = 0; s < NS; ++s) { sp += mp[s]; sn += mn[s]; si += infon[s]; }
        sp /= 12.f; sn /= 12.f; si /= 12.f;
        float loss = fmaxf(0.2f + sn - sp, 0.f) + 0.25f * (-si);
        out[0] = loss;
    }
}

extern "C" void kernel_launch(void* const* d_in, const int* in_sizes, int n_in,
                              void* d_out, int out_size, void* d_ws, size_t ws_size,
                              hipStream_t stream) {
    const float* fg = (const float*)d_in[0];   // [10,768]
    const float* bg = (const float*)d_in[1];   // [10,768]
    const float* F  = (const float*)d_in[2];   // [8,768,64,64]
    const float* M  = (const float*)d_in[3];   // [8,1,64,64]
    float* out = (float*)d_out;                // [1 + 7680 + 7680]

    float* w    = (float*)d_ws;
    ull*   cand = (ull*)(w + WS_CAND);
    float* fea  = w + WS_FEATS;
    float* pfg  = w + WS_PFG;
    float* pbg  = w + WS_PBG;

    k_scores<<<NBLK, 1024, 0, stream>>>(fg, bg, F, M, cand);
    k_gather<<<24, 256, 0, stream>>>(cand, F, fea);
    k_refine<<<2, 640, 0, stream>>>(fea, fg, bg, pfg, pbg, out);
    k_loss  <<<1, 1024, 0, stream>>>(fea, pfg, pbg, out);
}